// Round 1
// baseline (776.974 us; speedup 1.0000x reference)
//
#include <hip/hip_runtime.h>

// CRF forward: B=512 batches, T=1024 steps, N=64 states.
// One 64-lane wave per batch. Lane j owns alpha_j and column j of
// E = exp(transitions) (64 VGPRs). Per step:
//   m = wavemax(alpha); p = exp(alpha - m)  [lane-parallel]
//   z_j = sum_i p_i * E[i][j]               [p via LDS broadcast]
//   alpha_j = m + u_t[j] + log(z_j)
// Loop runs only to len(b) (mask is wave-uniform -> skip dead steps).

constexpr int Tt = 1024;
constexpr int Nn = 64;

__global__ __launch_bounds__(64) void crf_fwd(
    const float* __restrict__ unary,
    const int*   __restrict__ lengths,
    const float* __restrict__ trans,
    float*       __restrict__ out)
{
    const int b = blockIdx.x;
    const int j = threadIdx.x;

    __shared__ float sh_p[Nn];

    // Column j of exp(transitions): E[i] = exp(trans[i][j]); coalesced loads.
    float Ecol[Nn];
    #pragma unroll
    for (int i = 0; i < Nn; ++i) {
        Ecol[i] = __expf(trans[i * Nn + j]);
    }

    int len = lengths[b];
    if (len < 1) len = 1;
    if (len > Tt) len = Tt;

    const float* ub = unary + (size_t)b * Tt * Nn;
    float alpha = ub[j];  // t = 0

    for (int t = 1; t < len; ++t) {
        float u = ub[t * Nn + j];

        // wave-wide max of alpha
        float m = alpha;
        #pragma unroll
        for (int k = 32; k >= 1; k >>= 1)
            m = fmaxf(m, __shfl_xor(m, k, 64));

        float p = __expf(alpha - m);
        sh_p[j] = p;
        __syncthreads();

        float a0 = 0.f, a1 = 0.f, a2 = 0.f, a3 = 0.f;
        #pragma unroll
        for (int i = 0; i < Nn; i += 4) {
            a0 = __builtin_fmaf(sh_p[i + 0], Ecol[i + 0], a0);
            a1 = __builtin_fmaf(sh_p[i + 1], Ecol[i + 1], a1);
            a2 = __builtin_fmaf(sh_p[i + 2], Ecol[i + 2], a2);
            a3 = __builtin_fmaf(sh_p[i + 3], Ecol[i + 3], a3);
        }
        float z = (a0 + a1) + (a2 + a3);

        alpha = m + u + __logf(z);
        __syncthreads();  // protect sh_p before next iteration's write
    }

    // out[b] = logsumexp_j(alpha_j)
    float m = alpha;
    #pragma unroll
    for (int k = 32; k >= 1; k >>= 1)
        m = fmaxf(m, __shfl_xor(m, k, 64));
    float e = __expf(alpha - m);
    float s = e;
    #pragma unroll
    for (int k = 32; k >= 1; k >>= 1)
        s += __shfl_xor(s, k, 64);
    if (j == 0) out[b] = m + __logf(s);
}

extern "C" void kernel_launch(void* const* d_in, const int* in_sizes, int n_in,
                              void* d_out, int out_size, void* d_ws, size_t ws_size,
                              hipStream_t stream) {
    const float* unary   = (const float*)d_in[0];
    const int*   lengths = (const int*)d_in[1];
    const float* trans   = (const float*)d_in[2];
    float*       out     = (float*)d_out;

    const int Bb = in_sizes[1];  // 512
    crf_fwd<<<Bb, 64, 0, stream>>>(unary, lengths, trans, out);
}

// Round 2
// 600.545 us; speedup vs baseline: 1.2938x; 1.2938x over previous
//
#include <hip/hip_runtime.h>

// CRF forward: B=512, T=1024, N=64. One 64-lane wave per batch.
// Round 2 changes vs round 1:
//  - u prefetched 4 steps ahead (HBM ~900cy latency was serialized per step)
//  - wave-max replaced by readfirstlane offset (offset-invariant recurrence;
//    lane spread of alpha bounded ~12, exp(12)=1.6e5 safe in fp32)
//  - p broadcast read as float4 (16x ds_read_b128 instead of 64x ds_read_b32)
//  - ping-pong p buffer: one __syncthreads per step (free for 1-wave block)

constexpr int Tt = 1024;
constexpr int Nn = 64;

__global__ __launch_bounds__(64) void crf_fwd(
    const float* __restrict__ unary,
    const int*   __restrict__ lengths,
    const float* __restrict__ trans,
    float*       __restrict__ out)
{
    const int b = blockIdx.x;
    const int j = threadIdx.x;

    __shared__ float sh_p[2][Nn];

    // Column j of E = exp(transitions): coalesced, one-time.
    float Ecol[Nn];
    #pragma unroll
    for (int i = 0; i < Nn; ++i)
        Ecol[i] = __expf(trans[i * Nn + j]);

    int len = lengths[b];
    len = len < 1 ? 1 : (len > Tt ? Tt : len);

    const float* ub = unary + (size_t)b * Tt * Nn;
    float alpha = ub[j];  // t = 0

    // Prefetch u for steps t0..t0+3 (clamped index stays in this batch's row).
    float u_cur[4];
    #pragma unroll
    for (int k = 0; k < 4; ++k) {
        int t = 1 + k;
        u_cur[k] = ub[(t < Tt ? t : Tt - 1) * Nn + j];
    }

    int buf = 0;
    for (int t0 = 1; t0 < len; t0 += 4) {
        // Issue next chunk's loads before compute (prefetch distance = 4 steps).
        float u_nxt[4];
        #pragma unroll
        for (int k = 0; k < 4; ++k) {
            int t = t0 + 4 + k;
            u_nxt[k] = ub[(t < Tt ? t : Tt - 1) * Nn + j];
        }

        #pragma unroll
        for (int k = 0; k < 4; ++k) {
            int t = t0 + k;
            if (t >= len) break;  // wave-uniform

            // Wave-uniform offset: lane 0's alpha (spread bounded, no overflow).
            float s = __builtin_amdgcn_readfirstlane(__float_as_uint(alpha));
            float sf = __uint_as_float((unsigned)__builtin_amdgcn_readfirstlane(__float_as_uint(alpha)));
            (void)s;
            float p = __expf(alpha - sf);
            sh_p[buf][j] = p;
            __syncthreads();

            const float4* p4 = (const float4*)sh_p[buf];
            float a0 = 0.f, a1 = 0.f, a2 = 0.f, a3 = 0.f;
            #pragma unroll
            for (int i = 0; i < Nn / 4; ++i) {
                float4 pv = p4[i];
                a0 = __builtin_fmaf(pv.x, Ecol[4 * i + 0], a0);
                a1 = __builtin_fmaf(pv.y, Ecol[4 * i + 1], a1);
                a2 = __builtin_fmaf(pv.z, Ecol[4 * i + 2], a2);
                a3 = __builtin_fmaf(pv.w, Ecol[4 * i + 3], a3);
            }
            float z = (a0 + a1) + (a2 + a3);

            alpha = sf + u_cur[k] + __logf(z);
            buf ^= 1;  // ping-pong: next write goes to the other buffer
        }

        #pragma unroll
        for (int k = 0; k < 4; ++k) u_cur[k] = u_nxt[k];
    }

    // out[b] = logsumexp_j(alpha_j) — exact max here (one-time cost).
    float m = alpha;
    #pragma unroll
    for (int k = 32; k >= 1; k >>= 1)
        m = fmaxf(m, __shfl_xor(m, k, 64));
    float e = __expf(alpha - m);
    float ssum = e;
    #pragma unroll
    for (int k = 32; k >= 1; k >>= 1)
        ssum += __shfl_xor(ssum, k, 64);
    if (j == 0) out[b] = m + __logf(ssum);
}

extern "C" void kernel_launch(void* const* d_in, const int* in_sizes, int n_in,
                              void* d_out, int out_size, void* d_ws, size_t ws_size,
                              hipStream_t stream) {
    const float* unary   = (const float*)d_in[0];
    const int*   lengths = (const int*)d_in[1];
    const float* trans   = (const float*)d_in[2];
    float*       out     = (float*)d_out;

    const int Bb = in_sizes[1];  // 512
    crf_fwd<<<Bb, 64, 0, stream>>>(unary, lengths, trans, out);
}

// Round 3
// 420.415 us; speedup vs baseline: 1.8481x; 1.4285x over previous
//
#include <hip/hip_runtime.h>

// CRF forward: B=512, T=1024, N=64. One 64-lane wave per batch.
// Round 3 changes vs round 2:
//  - E = exp(transitions) column j held in 16 NAMED float4s -> guaranteed
//    VGPRs. (Round 2's Ecol[64] array was NOT promoted: VGPR_Count=52 proves
//    it lived in scratch; per-step scratch reloads were the hidden cost.)
//  - No LDS, no __syncthreads: p broadcast via v_readlane (constant lane
//    index, all lanes active). Removing the barrier removes the implicit
//    s_waitcnt vmcnt(0) drain, so the u-prefetch finally stays in flight.

constexpr int Tt = 1024;
constexpr int Nn = 64;

#define LOADE(K) make_float4(__expf(trans[(4*(K)+0)*Nn+j]), \
                             __expf(trans[(4*(K)+1)*Nn+j]), \
                             __expf(trans[(4*(K)+2)*Nn+j]), \
                             __expf(trans[(4*(K)+3)*Nn+j]))

// broadcast p from lane L (readlane: uniform result, ignores exec; all 64
// lanes are always active here)
#define RL(L) __uint_as_float((unsigned)__builtin_amdgcn_readlane((int)__float_as_uint(p), (L)))

#define FMA4(K, EV)                          \
    a0 = __builtin_fmaf(RL(4*(K)+0), (EV).x, a0); \
    a1 = __builtin_fmaf(RL(4*(K)+1), (EV).y, a1); \
    a2 = __builtin_fmaf(RL(4*(K)+2), (EV).z, a2); \
    a3 = __builtin_fmaf(RL(4*(K)+3), (EV).w, a3);

__global__ __launch_bounds__(64) void crf_fwd(
    const float* __restrict__ unary,
    const int*   __restrict__ lengths,
    const float* __restrict__ trans,
    float*       __restrict__ out)
{
    const int b = blockIdx.x;
    const int j = threadIdx.x;

    // Column j of E = exp(transitions), in named registers.
    float4 e0  = LOADE(0),  e1  = LOADE(1),  e2  = LOADE(2),  e3  = LOADE(3);
    float4 e4  = LOADE(4),  e5  = LOADE(5),  e6  = LOADE(6),  e7  = LOADE(7);
    float4 e8  = LOADE(8),  e9  = LOADE(9),  e10 = LOADE(10), e11 = LOADE(11);
    float4 e12 = LOADE(12), e13 = LOADE(13), e14 = LOADE(14), e15 = LOADE(15);

    int len = lengths[b];
    len = len < 1 ? 1 : (len > Tt ? Tt : len);

    const float* ub = unary + (size_t)b * Tt * Nn;
    float alpha = ub[j];  // t = 0

    // Prefetch u for steps 1..4 (clamped indices stay inside this batch row).
    float u_cur[4];
    #pragma unroll
    for (int k = 0; k < 4; ++k) {
        int t = 1 + k;
        u_cur[k] = ub[(t < Tt ? t : Tt - 1) * Nn + j];
    }

    for (int t0 = 1; t0 < len; t0 += 4) {
        // Issue next chunk's loads (prefetch distance 4-8 steps; no barrier
        // anywhere, so these stay outstanding across the whole chunk).
        float u_nxt[4];
        #pragma unroll
        for (int k = 0; k < 4; ++k) {
            int t = t0 + 4 + k;
            u_nxt[k] = ub[(t < Tt ? t : Tt - 1) * Nn + j];
        }

        #pragma unroll
        for (int k = 0; k < 4; ++k) {
            if (t0 + k >= len) break;  // wave-uniform

            // Wave-uniform offset (offset-invariant recurrence; spread of
            // alpha across lanes is bounded ~12, exp(12) safe in fp32).
            float sf = __uint_as_float(
                (unsigned)__builtin_amdgcn_readfirstlane((int)__float_as_uint(alpha)));
            float p = __expf(alpha - sf);

            float a0 = 0.f, a1 = 0.f, a2 = 0.f, a3 = 0.f;
            FMA4(0,  e0);  FMA4(1,  e1);  FMA4(2,  e2);  FMA4(3,  e3);
            FMA4(4,  e4);  FMA4(5,  e5);  FMA4(6,  e6);  FMA4(7,  e7);
            FMA4(8,  e8);  FMA4(9,  e9);  FMA4(10, e10); FMA4(11, e11);
            FMA4(12, e12); FMA4(13, e13); FMA4(14, e14); FMA4(15, e15);
            float z = (a0 + a1) + (a2 + a3);

            alpha = sf + u_cur[k] + __logf(z);
        }

        #pragma unroll
        for (int k = 0; k < 4; ++k) u_cur[k] = u_nxt[k];
    }

    // out[b] = logsumexp_j(alpha_j) — exact max (one-time cost).
    float m = alpha;
    #pragma unroll
    for (int k = 32; k >= 1; k >>= 1)
        m = fmaxf(m, __shfl_xor(m, k, 64));
    float e = __expf(alpha - m);
    float ssum = e;
    #pragma unroll
    for (int k = 32; k >= 1; k >>= 1)
        ssum += __shfl_xor(ssum, k, 64);
    if (j == 0) out[b] = m + __logf(ssum);
}

extern "C" void kernel_launch(void* const* d_in, const int* in_sizes, int n_in,
                              void* d_out, int out_size, void* d_ws, size_t ws_size,
                              hipStream_t stream) {
    const float* unary   = (const float*)d_in[0];
    const int*   lengths = (const int*)d_in[1];
    const float* trans   = (const float*)d_in[2];
    float*       out     = (float*)d_out;

    const int Bb = in_sizes[1];  // 512
    crf_fwd<<<Bb, 64, 0, stream>>>(unary, lengths, trans, out);
}

// Round 4
// 420.232 us; speedup vs baseline: 1.8489x; 1.0004x over previous
//
#include <hip/hip_runtime.h>

// CRF forward: B=512, T=1024, N=64. One 64-lane wave per batch.
// Round 4 change vs round 3 (single variable):
//  - __launch_bounds__(64, 1): round 3's VGPR_Count=44 proved the compiler
//    capped registers for a default occupancy target and spilled E to
//    scratch (the ~530 cy/step stall). Min-1-wave/EU frees the full VGPR
//    budget so the 64 E values stay register-resident.

constexpr int Tt = 1024;
constexpr int Nn = 64;

#define LOADE(K) make_float4(__expf(trans[(4*(K)+0)*Nn+j]), \
                             __expf(trans[(4*(K)+1)*Nn+j]), \
                             __expf(trans[(4*(K)+2)*Nn+j]), \
                             __expf(trans[(4*(K)+3)*Nn+j]))

// broadcast p from lane L (all 64 lanes always active)
#define RL(L) __uint_as_float((unsigned)__builtin_amdgcn_readlane((int)__float_as_uint(p), (L)))

#define FMA4(K, EV)                               \
    a0 = __builtin_fmaf(RL(4*(K)+0), (EV).x, a0); \
    a1 = __builtin_fmaf(RL(4*(K)+1), (EV).y, a1); \
    a2 = __builtin_fmaf(RL(4*(K)+2), (EV).z, a2); \
    a3 = __builtin_fmaf(RL(4*(K)+3), (EV).w, a3);

__global__ __launch_bounds__(64, 1) void crf_fwd(
    const float* __restrict__ unary,
    const int*   __restrict__ lengths,
    const float* __restrict__ trans,
    float*       __restrict__ out)
{
    const int b = blockIdx.x;
    const int j = threadIdx.x;

    // Column j of E = exp(transitions), register-resident.
    float4 e0  = LOADE(0),  e1  = LOADE(1),  e2  = LOADE(2),  e3  = LOADE(3);
    float4 e4  = LOADE(4),  e5  = LOADE(5),  e6  = LOADE(6),  e7  = LOADE(7);
    float4 e8  = LOADE(8),  e9  = LOADE(9),  e10 = LOADE(10), e11 = LOADE(11);
    float4 e12 = LOADE(12), e13 = LOADE(13), e14 = LOADE(14), e15 = LOADE(15);

    int len = lengths[b];
    len = len < 1 ? 1 : (len > Tt ? Tt : len);

    const float* ub = unary + (size_t)b * Tt * Nn;
    float alpha = ub[j];  // t = 0

    // Prefetch u for steps 1..4 (clamped indices stay inside this batch row).
    float u_cur[4];
    #pragma unroll
    for (int k = 0; k < 4; ++k) {
        int t = 1 + k;
        u_cur[k] = ub[(t < Tt ? t : Tt - 1) * Nn + j];
    }

    for (int t0 = 1; t0 < len; t0 += 4) {
        // Next chunk's loads stay in flight (no barrier anywhere in the loop).
        float u_nxt[4];
        #pragma unroll
        for (int k = 0; k < 4; ++k) {
            int t = t0 + 4 + k;
            u_nxt[k] = ub[(t < Tt ? t : Tt - 1) * Nn + j];
        }

        #pragma unroll
        for (int k = 0; k < 4; ++k) {
            if (t0 + k >= len) break;  // wave-uniform

            // Wave-uniform offset (recurrence is offset-invariant; lane
            // spread of alpha bounded ~12, exp(12) safe in fp32).
            float sf = __uint_as_float(
                (unsigned)__builtin_amdgcn_readfirstlane((int)__float_as_uint(alpha)));
            float p = __expf(alpha - sf);

            float a0 = 0.f, a1 = 0.f, a2 = 0.f, a3 = 0.f;
            FMA4(0,  e0);  FMA4(1,  e1);  FMA4(2,  e2);  FMA4(3,  e3);
            FMA4(4,  e4);  FMA4(5,  e5);  FMA4(6,  e6);  FMA4(7,  e7);
            FMA4(8,  e8);  FMA4(9,  e9);  FMA4(10, e10); FMA4(11, e11);
            FMA4(12, e12); FMA4(13, e13); FMA4(14, e14); FMA4(15, e15);
            float z = (a0 + a1) + (a2 + a3);

            alpha = sf + u_cur[k] + __logf(z);
        }

        #pragma unroll
        for (int k = 0; k < 4; ++k) u_cur[k] = u_nxt[k];
    }

    // out[b] = logsumexp_j(alpha_j) — exact max (one-time cost).
    float m = alpha;
    #pragma unroll
    for (int k = 32; k >= 1; k >>= 1)
        m = fmaxf(m, __shfl_xor(m, k, 64));
    float e = __expf(alpha - m);
    float ssum = e;
    #pragma unroll
    for (int k = 32; k >= 1; k >>= 1)
        ssum += __shfl_xor(ssum, k, 64);
    if (j == 0) out[b] = m + __logf(ssum);
}

extern "C" void kernel_launch(void* const* d_in, const int* in_sizes, int n_in,
                              void* d_out, int out_size, void* d_ws, size_t ws_size,
                              hipStream_t stream) {
    const float* unary   = (const float*)d_in[0];
    const int*   lengths = (const int*)d_in[1];
    const float* trans   = (const float*)d_in[2];
    float*       out     = (float*)d_out;

    const int Bb = in_sizes[1];  // 512
    crf_fwd<<<Bb, 64, 0, stream>>>(unary, lengths, trans, out);
}